// Round 5
// baseline (252.361 us; speedup 1.0000x reference)
//
#include <hip/hip_runtime.h>

// Problem constants
constexpr int NCELLS = 16384 * 49;            // 802816 cells, 30 floats each

typedef float v2f __attribute__((ext_vector_type(2)));

__global__ void zero_out_kernel(float* out) {
    if (threadIdx.x < 5) out[threadIdx.x] = 0.0f;
}

__global__ __launch_bounds__(256) void yolo_loss_kernel(
    const float* __restrict__ pred,
    const float* __restrict__ tgt,
    float* __restrict__ out)
{
    const int c = blockIdx.x * blockDim.x + threadIdx.x;   // exactly NCELLS threads

    // Single-use streaming data: nontemporal float2 loads (no L1 retention).
    const v2f* pp = reinterpret_cast<const v2f*>(pred) + (size_t)c * 15;
    const v2f* tp = reinterpret_cast<const v2f*>(tgt)  + (size_t)c * 15;

    float p[30], t[30];
    #pragma unroll
    for (int j = 0; j < 15; ++j) {
        v2f a = __builtin_nontemporal_load(pp + j);
        p[2*j] = a.x; p[2*j+1] = a.y;
    }
    #pragma unroll
    for (int j = 0; j < 15; ++j) {
        v2f b = __builtin_nontemporal_load(tp + j);
        t[2*j] = b.x; t[2*j+1] = b.y;
    }

    const float tconf = t[4];                 // 0.0 or 1.0
    const float m  = (tconf > 0.0f)  ? 1.0f : 0.0f;
    const float nm = (tconf == 0.0f) ? 1.0f : 0.0f;

    // IoU of each pred box vs target box 0 (channels 0..3)
    const float t0x1 = t[0], t0y1 = t[1], t0x2 = t[2], t0y2 = t[3];
    const float a2 = (t0x2 - t0x1) * (t0y2 - t0y1);

    float iou[2];
    #pragma unroll
    for (int b = 0; b < 2; ++b) {
        const float px1 = p[5*b+0], py1 = p[5*b+1];
        const float px2 = p[5*b+2], py2 = p[5*b+3];
        const float ltx = fmaxf(px1, t0x1), lty = fmaxf(py1, t0y1);
        const float rbx = fminf(px2, t0x2), rby = fminf(py2, t0y2);
        const float wx = fmaxf(rbx - ltx, 0.0f), wy = fmaxf(rby - lty, 0.0f);
        const float inter = wx * wy;
        const float a1 = (px2 - px1) * (py2 - py1);
        iou[b] = inter / (a1 + a2 - inter);
    }

    const float max_iou = fmaxf(iou[0], iou[1]);
    const int r = (iou[0] >= iou[1]) ? 0 : 5;   // first index wins ties

    float acc0, acc1, acc2, acc3, acc4;
    {   // xy
        const float dx = p[r+0] - t[r+0];
        const float dy = p[r+1] - t[r+1];
        acc0 = m * (dx*dx + dy*dy);
    }
    {   // wh (sqrt space; inputs in (0.05, 0.95) so sqrt args > 0)
        const float dw = sqrtf(p[r+2]) - sqrtf(t[r+2]);
        const float dh = sqrtf(p[r+3]) - sqrtf(t[r+3]);
        acc1 = m * (dw*dw + dh*dh);
    }
    {   // obj
        const float d = p[r+4] - max_iou;
        acc2 = m * d * d;
    }
    {   // noobj (channels 4, 9)
        const float d0 = p[4] - t[4];
        const float d1 = p[9] - t[9];
        acc3 = nm * (d0*d0 + d1*d1);
    }
    {   // class (channels 10..29)
        float cl = 0.f;
        #pragma unroll
        for (int k = 10; k < 30; ++k) {
            const float d = p[k] - t[k];
            cl += d * d;
        }
        acc4 = m * cl;
    }

    // ---- reduction: wave (64) -> block -> global atomics ----
    float acc[5] = {acc0, acc1, acc2, acc3, acc4};
    __shared__ float wave_sums[4][5];
    const int lane = threadIdx.x & 63;
    const int wv   = threadIdx.x >> 6;

    #pragma unroll
    for (int i = 0; i < 5; ++i) {
        float v = acc[i];
        #pragma unroll
        for (int o = 32; o > 0; o >>= 1)
            v += __shfl_down(v, o, 64);
        if (lane == 0) wave_sums[wv][i] = v;
    }
    __syncthreads();

    if (threadIdx.x < 5) {
        const float v = wave_sums[0][threadIdx.x] + wave_sums[1][threadIdx.x]
                      + wave_sums[2][threadIdx.x] + wave_sums[3][threadIdx.x];
        atomicAdd(out + threadIdx.x, v);
    }
}

extern "C" void kernel_launch(void* const* d_in, const int* in_sizes, int n_in,
                              void* d_out, int out_size, void* d_ws, size_t ws_size,
                              hipStream_t stream) {
    const float* pred = (const float*)d_in[0];
    const float* tgt  = (const float*)d_in[1];
    float* out = (float*)d_out;

    hipLaunchKernelGGL(zero_out_kernel, dim3(1), dim3(64), 0, stream, out);

    // One cell per thread: 3136 blocks x 256 threads = 802816 threads exactly.
    // 12544 waves -> full wave residency per CU (VGPR-light kernel).
    hipLaunchKernelGGL(yolo_loss_kernel, dim3(NCELLS / 256), dim3(256), 0, stream,
                       pred, tgt, out);
}

// Round 6
// 208.223 us; speedup vs baseline: 1.2120x; 1.2120x over previous
//
#include <hip/hip_runtime.h>

// Problem constants
constexpr int S = 7, NB = 2, C = 20, E = 30;      // E = NB*5 + C = 30
constexpr int BATCH = 16384;
constexpr int NCELLS = BATCH * S * S;             // 802816
constexpr int CW   = 30;                          // words per cell
constexpr int TILE = 64;                          // cells per wave tile
constexpr int TF2  = TILE * CW / 2;               // 960 float2 per tensor tile

__global__ void zero_out_kernel(float* out) {
    if (threadIdx.x < 5) out[threadIdx.x] = 0.0f;
}

__global__ __launch_bounds__(256, 2) void yolo_loss_kernel(
    const float* __restrict__ pred,
    const float* __restrict__ tgt,
    float* __restrict__ out)
{
    // Per-wave staging: pred tile (960 float2) + tgt tile (960 float2) = 15360 B/wave
    __shared__ float2 lds[4][2 * TF2];            // 61440 B -> 2 blocks/CU
    const int lane = threadIdx.x & 63;
    const int wv   = threadIdx.x >> 6;
    float2* lp = lds[wv];
    float2* lt = lds[wv] + TF2;

    const int wave_id = (blockIdx.x * blockDim.x + threadIdx.x) >> 6;
    const int nwaves  = (gridDim.x * blockDim.x) >> 6;
    const int ntiles  = NCELLS / TILE;            // 12544 (exact)

    float acc0 = 0.f, acc1 = 0.f, acc2 = 0.f, acc3 = 0.f, acc4 = 0.f;

    for (int tile = wave_id; tile < ntiles; tile += nwaves) {
        const float2* gp = reinterpret_cast<const float2*>(pred) + (size_t)tile * TF2;
        const float2* gt = reinterpret_cast<const float2*>(tgt)  + (size_t)tile * TF2;

        // Coalesced global -> LDS staging: 15 float2 per lane per tensor,
        // consecutive lanes -> consecutive 8B -> 512 B/wave-instruction.
        #pragma unroll
        for (int j = 0; j < 15; ++j) {
            lp[j * 64 + lane] = gp[j * 64 + lane];
            lt[j * 64 + lane] = gt[j * 64 + lane];
        }
        // Wave-synchronous: drain LDS writes before reads (LDS ops in-order
        // per wave; clobber blocks compiler reordering).
        asm volatile("s_waitcnt lgkmcnt(0)" ::: "memory");

        // Each lane reads its own cell: 15 x b64, stride 30 words -> 4-phase
        // (conflict-optimal for b64 on 32 banks).
        float p[30], t[30];
        const float2* myp = lp + lane * 15;
        const float2* myt = lt + lane * 15;
        #pragma unroll
        for (int j = 0; j < 15; ++j) {
            float2 a = myp[j]; p[2*j] = a.x; p[2*j+1] = a.y;
            float2 b = myt[j]; t[2*j] = b.x; t[2*j+1] = b.y;
        }

        const float tconf = t[4];                 // 0.0 or 1.0
        const float m  = (tconf > 0.0f)  ? 1.0f : 0.0f;
        const float nm = (tconf == 0.0f) ? 1.0f : 0.0f;

        // IoU of each pred box vs target box 0 (channels 0..3)
        const float t0x1 = t[0], t0y1 = t[1], t0x2 = t[2], t0y2 = t[3];
        const float a2 = (t0x2 - t0x1) * (t0y2 - t0y1);

        float iou[2];
        #pragma unroll
        for (int b = 0; b < 2; ++b) {
            const float px1 = p[5*b+0], py1 = p[5*b+1];
            const float px2 = p[5*b+2], py2 = p[5*b+3];
            const float ltx = fmaxf(px1, t0x1), lty = fmaxf(py1, t0y1);
            const float rbx = fminf(px2, t0x2), rby = fminf(py2, t0y2);
            const float wx = fmaxf(rbx - ltx, 0.0f), wy = fmaxf(rby - lty, 0.0f);
            const float inter = wx * wy;
            const float a1 = (px2 - px1) * (py2 - py1);
            iou[b] = inter / (a1 + a2 - inter);
        }

        const float max_iou = fmaxf(iou[0], iou[1]);
        const int r = (iou[0] >= iou[1]) ? 0 : 5;   // first index wins ties

        {   // xy
            const float dx = p[r+0] - t[r+0];
            const float dy = p[r+1] - t[r+1];
            acc0 += m * (dx*dx + dy*dy);
        }
        {   // wh (sqrt space; inputs in (0.05, 0.95) so sqrt args > 0)
            const float dw = sqrtf(p[r+2]) - sqrtf(t[r+2]);
            const float dh = sqrtf(p[r+3]) - sqrtf(t[r+3]);
            acc1 += m * (dw*dw + dh*dh);
        }
        {   // obj
            const float d = p[r+4] - max_iou;
            acc2 += m * d * d;
        }
        {   // noobj (channels 4, 9)
            const float d0 = p[4] - t[4];
            const float d1 = p[9] - t[9];
            acc3 += nm * (d0*d0 + d1*d1);
        }
        {   // class (channels 10..29)
            float cl = 0.f;
            #pragma unroll
            for (int k = 10; k < 30; ++k) {
                const float d = p[k] - t[k];
                cl += d * d;
            }
            acc4 += m * cl;
        }
    }

    // ---- reduction: wave (64) -> block -> global atomics ----
    float acc[5] = {acc0, acc1, acc2, acc3, acc4};
    __shared__ float wave_sums[4][5];
    #pragma unroll
    for (int i = 0; i < 5; ++i) {
        float v = acc[i];
        #pragma unroll
        for (int o = 32; o > 0; o >>= 1)
            v += __shfl_down(v, o, 64);
        if (lane == 0) wave_sums[wv][i] = v;
    }
    __syncthreads();

    if (threadIdx.x < 5) {
        const float v = wave_sums[0][threadIdx.x] + wave_sums[1][threadIdx.x]
                      + wave_sums[2][threadIdx.x] + wave_sums[3][threadIdx.x];
        atomicAdd(out + threadIdx.x, v);
    }
}

extern "C" void kernel_launch(void* const* d_in, const int* in_sizes, int n_in,
                              void* d_out, int out_size, void* d_ws, size_t ws_size,
                              hipStream_t stream) {
    const float* pred = (const float*)d_in[0];
    const float* tgt  = (const float*)d_in[1];
    float* out = (float*)d_out;

    hipLaunchKernelGGL(zero_out_kernel, dim3(1), dim3(64), 0, stream, out);

    // 512 blocks x 256 threads = 2048 waves; 2 blocks/CU resident (LDS-bound)
    hipLaunchKernelGGL(yolo_loss_kernel, dim3(512), dim3(256), 0, stream,
                       pred, tgt, out);
}